// Round 1
// baseline (2724.822 us; speedup 1.0000x reference)
//
#include <hip/hip_runtime.h>
#include <stdint.h>

// Sparse top-k attention (B=4,N=2048,D=1024,H=16,DH=64, topk=64).
// Precision-critical path (selection must match numpy f32): q32/k32 via exact
// 3-word bf16-split MFMA GEMM; bulk dots in 1-word bf16 MFMA; exact f32
// recompute of the ~4 candidates within +-6e-3 of the rank-64 threshold.

typedef __attribute__((ext_vector_type(8))) short short8;
typedef __attribute__((ext_vector_type(4))) float floatx4;

#define Bn   4
#define Nn   2048
#define Hn   16
#define BHn  (Bn*Hn)

__device__ __forceinline__ float bf2f(unsigned short u) {
  union { unsigned int i; float f; } v; v.i = ((unsigned int)u) << 16; return v.f;
}
__device__ __forceinline__ unsigned short f2bf(float f) {
  union { float f; unsigned int i; } v; v.f = f;
  unsigned int r = v.i + 0x7fffu + ((v.i >> 16) & 1u);
  return (unsigned short)(r >> 16);
}
// monotone f32 <-> u32 key map (order-preserving)
__device__ __forceinline__ unsigned int f2k(float f) {
  unsigned int b = __float_as_uint(f);
  return (b & 0x80000000u) ? ~b : (b | 0x80000000u);
}
__device__ __forceinline__ float k2f(unsigned int k) {
  unsigned int b = (k & 0x80000000u) ? (k & 0x7fffffffu) : ~k;
  return __uint_as_float(b);
}
__device__ __forceinline__ floatx4 mfma16(short8 a, short8 b, floatx4 c) {
  return __builtin_amdgcn_mfma_f32_16x16x32_bf16(a, b, c, 0, 0, 0);
}
// exact 3-word bf16 split: x == hi + mid + lo (covers 24 mantissa bits)
__device__ __forceinline__ void split3(float x, unsigned short& h, unsigned short& m, unsigned short& l) {
  h = f2bf(x);
  float r = x - bf2f(h);
  m = f2bf(r);
  float r2 = r - bf2f(m);
  l = f2bf(r2);
}

// ---- W[K][N] f32 -> Wt{0,1,2}[N][K] bf16 split (T1==nullptr: 1-word only)
__global__ __launch_bounds__(256)
void transpose_split(const float* __restrict__ W,
                     unsigned short* __restrict__ T0,
                     unsigned short* __restrict__ T1,
                     unsigned short* __restrict__ T2,
                     int K, int Ncols)
{
  __shared__ float tile[32][33];
  int k0 = blockIdx.y * 32, n0 = blockIdx.x * 32;
  int tx = threadIdx.x & 31, ty = threadIdx.x >> 5;  // 32 x 8
  for (int s = 0; s < 32; s += 8)
    tile[ty + s][tx] = W[(size_t)(k0 + ty + s) * Ncols + n0 + tx];
  __syncthreads();
  for (int s = 0; s < 32; s += 8) {
    float x = tile[tx][ty + s];
    unsigned short h, m, l;
    split3(x, h, m, l);
    size_t o = (size_t)(n0 + ty + s) * K + k0 + tx;
    T0[o] = h;
    if (T1) { T1[o] = m; T2[o] = l; }
  }
}

__global__ __launch_bounds__(256)
void convert_bf16(const float* __restrict__ in, unsigned short* __restrict__ outp, int n) {
  int i = blockIdx.x * 256 + threadIdx.x;
  if (i < n) outp[i] = f2bf(in[i]);
}

// ---- GEMM C = A * Bt^T + bias.  NW=3: A f32 split on the fly (f32-fidelity
// via 6 MFMA terms).  NW=1: A bf16, 1 MFMA.  mode 0: QKV head-split layout
// (f32 + bf16 outputs); mode 1: plain f32 out.
template<int NW>
__global__ __launch_bounds__(256)
void gemm_k(const void* __restrict__ Ap,
            const unsigned short* __restrict__ B0,
            const unsigned short* __restrict__ B1,
            const unsigned short* __restrict__ B2,
            const float* __restrict__ bias,
            float* __restrict__ O32,
            unsigned short* __restrict__ Obf,
            unsigned short* __restrict__ Vbf,
            int M, int Ncols, int K, float scale, int mode)
{
  __shared__ unsigned short lA[NW][128 * 40];
  __shared__ unsigned short lB[NW][128 * 40];
  const int tid = threadIdx.x;
  const int lane = tid & 63;
  const int m0 = blockIdx.y * 128, n0 = blockIdx.x * 128;
  const int wid = tid >> 6, wm = wid >> 1, wn = wid & 1;
  const int fr = lane & 15, fq = lane >> 4;
  floatx4 acc[4][4] = {};

  for (int k0 = 0; k0 < K; k0 += 32) {
    __syncthreads();
    #pragma unroll
    for (int p = 0; p < 2; p++) {
      int c = tid + p * 256;
      int row = c >> 2, kc = (c & 3) * 8;
      size_t go = (size_t)(m0 + row) * K + k0 + kc;
      if (NW == 1) {
        *(uint4*)&lA[0][row * 40 + kc] = *(const uint4*)&((const unsigned short*)Ap)[go];
      } else {
        const float* A = (const float*)Ap;
        float4 v0 = *(const float4*)&A[go];
        float4 v1 = *(const float4*)&A[go + 4];
        union { unsigned short u[8]; uint4 q; } hh, mm, ll;
        float xs[8] = {v0.x, v0.y, v0.z, v0.w, v1.x, v1.y, v1.z, v1.w};
        #pragma unroll
        for (int e = 0; e < 8; e++) split3(xs[e], hh.u[e], mm.u[e], ll.u[e]);
        *(uint4*)&lA[0][row * 40 + kc] = hh.q;
        *(uint4*)&lA[1][row * 40 + kc] = mm.q;
        *(uint4*)&lA[2][row * 40 + kc] = ll.q;
      }
      size_t bo = (size_t)(n0 + row) * K + k0 + kc;
      *(uint4*)&lB[0][row * 40 + kc] = *(const uint4*)&B0[bo];
      if (NW == 3) {
        *(uint4*)&lB[1][row * 40 + kc] = *(const uint4*)&B1[bo];
        *(uint4*)&lB[2][row * 40 + kc] = *(const uint4*)&B2[bo];
      }
    }
    __syncthreads();
    short8 af[NW][4], bfr[NW][4];
    #pragma unroll
    for (int s = 0; s < NW; s++)
      #pragma unroll
      for (int t = 0; t < 4; t++) {
        af[s][t]  = *(const short8*)&lA[s][(wm * 64 + t * 16 + fr) * 40 + 8 * fq];
        bfr[s][t] = *(const short8*)&lB[s][(wn * 64 + t * 16 + fr) * 40 + 8 * fq];
      }
    #pragma unroll
    for (int mi = 0; mi < 4; mi++)
      #pragma unroll
      for (int ni = 0; ni < 4; ni++) {
        acc[mi][ni] = mfma16(af[0][mi], bfr[0][ni], acc[mi][ni]);
        if (NW == 3) {
          acc[mi][ni] = mfma16(af[0][mi], bfr[1][ni], acc[mi][ni]);
          acc[mi][ni] = mfma16(af[1][mi], bfr[0][ni], acc[mi][ni]);
          acc[mi][ni] = mfma16(af[1][mi], bfr[1][ni], acc[mi][ni]);
          acc[mi][ni] = mfma16(af[0][mi], bfr[2][ni], acc[mi][ni]);
          acc[mi][ni] = mfma16(af[2][mi], bfr[0][ni], acc[mi][ni]);
        }
      }
  }
  // epilogue: C/D frag row=(lane>>4)*4+rg, col=lane&15  [m91-verified]
  #pragma unroll
  for (int mi = 0; mi < 4; mi++)
    #pragma unroll
    for (int ni = 0; ni < 4; ni++) {
      int nl = n0 + wn * 64 + ni * 16 + fr;
      float bv = bias[nl];
      #pragma unroll
      for (int rg = 0; rg < 4; rg++) {
        int ml = m0 + wm * 64 + mi * 16 + fq * 4 + rg;
        float val = (acc[mi][ni][rg] + bv) * scale;
        if (mode == 1) {
          O32[(size_t)ml * Ncols + nl] = val;
        } else {
          int bb = ml >> 11, ii = ml & 2047;
          if (nl < 1024) {
            int hh2 = nl >> 6, dd = nl & 63;
            size_t idx = (((size_t)bb * Hn + hh2) * Nn + ii) * 64 + dd;
            O32[idx] = val;
            Obf[idx] = f2bf(val);
          } else {
            int hh2 = (nl - 1024) >> 6, dd = nl & 63;
            size_t idx = (((size_t)bb * Hn + hh2) * Nn + ii) * 64 + dd;
            Vbf[idx] = f2bf(val);
          }
        }
      }
    }
}

// ---- attention: one WG (8 waves / 512 thr) handles 16 query rows of one (b,h)
#define WINW 0.006f

__global__ __launch_bounds__(512)
void attn_k(const unsigned short* __restrict__ qbf,
            const unsigned short* __restrict__ kbf,
            const unsigned short* __restrict__ vbf,
            const float* __restrict__ q32,
            const float* __restrict__ k32,
            const float* __restrict__ rel32,
            const unsigned short* __restrict__ relbf,
            const float* __restrict__ gating,
            const int* __restrict__ topkp,
            unsigned short* __restrict__ inner)
{
  extern __shared__ char smem[];
  float* S = (float*)smem;                                    // [16][2052] f32
  unsigned short* Kt = (unsigned short*)(smem + 16 * 2052 * 4); // [128][72] bf16
  unsigned short* qE = Kt + 128 * 72;                         // [16][264] bf16

  const int ib = blockIdx.x, bh = blockIdx.y;
  const int i0 = ib * 16;
  const int b = bh >> 4, h = bh & 15;
  const int lane = threadIdx.x & 63, w = threadIdx.x >> 6;
  const int fr = lane & 15, fq = lane >> 4;
  const int topk = topkp[0];

  // q A-fragments (A row = lane&15, k = 8*(lane>>4)+e)
  const size_t qoff = ((size_t)bh * Nn + i0) * 64;
  const short8 aq0 = *(const short8*)&qbf[qoff + (size_t)fr * 64 + 8 * fq];
  const short8 aq1 = *(const short8*)&qbf[qoff + (size_t)fr * 64 + 32 + 8 * fq];

  // qE[i_local][r] = q_s . rel[r]   (2 r-strips of 16 per wave)
  #pragma unroll
  for (int rs = 0; rs < 2; rs++) {
    int r0 = (w * 2 + rs) * 16;
    short8 rb0 = *(const short8*)&relbf[(size_t)(r0 + fr) * 64 + 8 * fq];
    short8 rb1 = *(const short8*)&relbf[(size_t)(r0 + fr) * 64 + 32 + 8 * fq];
    floatx4 c = {};
    c = mfma16(aq0, rb0, c);
    c = mfma16(aq1, rb1, c);
    #pragma unroll
    for (int rg = 0; rg < 4; rg++)
      qE[(fq * 4 + rg) * 264 + r0 + fr] = f2bf(c[rg]);
  }

  // S[i_local][j] = q_s . k_j over all 2048 j (16 tiles of 128)
  for (int jt = 0; jt < 16; jt++) {
    __syncthreads();
    #pragma unroll
    for (int p = 0; p < 2; p++) {
      int c = (int)threadIdx.x + p * 512;
      int row = c >> 3, dc = (c & 7) * 8;
      *(uint4*)&Kt[row * 72 + dc] =
        *(const uint4*)&kbf[((size_t)bh * Nn + jt * 128 + row) * 64 + dc];
    }
    __syncthreads();
    short8 kb0 = *(const short8*)&Kt[(w * 16 + fr) * 72 + 8 * fq];
    short8 kb1 = *(const short8*)&Kt[(w * 16 + fr) * 72 + 32 + 8 * fq];
    floatx4 c = {};
    c = mfma16(aq0, kb0, c);
    c = mfma16(aq1, kb1, c);
    #pragma unroll
    for (int rg = 0; rg < 4; rg++)
      S[(fq * 4 + rg) * 2052 + jt * 128 + w * 16 + fr] = c[rg];
  }
  __syncthreads();

  // per-row selection + softmax + PV (wave w owns rows 2w, 2w+1)
  #pragma unroll 1
  for (int rr = 0; rr < 2; rr++) {
    const int r = w * 2 + rr;
    const int i = i0 + r;
    unsigned int key[32];
    #pragma unroll
    for (int e = 0; e < 32; e++) {
      int j = lane + 64 * e;
      int ridx = i - j + 256;
      ridx = ridx < 0 ? 0 : (ridx > 255 ? 255 : ridx);
      float s = S[r * 2052 + j] + bf2f(qE[r * 264 + ridx]);
      key[e] = f2k(s);
    }
    // row max
    unsigned int kmx = 0;
    #pragma unroll
    for (int e = 0; e < 32; e++) kmx = key[e] > kmx ? key[e] : kmx;
    #pragma unroll
    for (int d = 1; d < 64; d <<= 1) {
      unsigned int o = (unsigned int)__shfl_xor((int)kmx, d);
      kmx = o > kmx ? o : kmx;
    }
    const float Mrow = k2f(kmx);
    // 32-bit binary search for rank-topk key
    unsigned int cur = 0;
    for (int bit = 31; bit >= 0; bit--) {
      unsigned int u = cur | (1u << bit);
      int cnt = 0;
      #pragma unroll
      for (int e = 0; e < 32; e++) cnt += (key[e] >= u) ? 1 : 0;
      #pragma unroll
      for (int d = 1; d < 64; d <<= 1) cnt += __shfl_xor(cnt, d);
      if (cnt >= topk) cur = u;
    }
    const float tthr = k2f(cur);
    const unsigned int hik = f2k(tthr + WINW);
    const unsigned int lok = f2k(tthr - WINW);

    // LDS scratch aliased into this row's S span (S already consumed to regs)
    int*   Jc = (int*)&S[r * 2052 + 0];     // candidate j      [32]
    float* Sx = &S[r * 2052 + 32];          // candidate exact  [32]
    float* Pl = &S[r * 2052 + 64];          // kept raw p       [96]
    int*   Jl = (int*)&S[r * 2052 + 160];   // kept j           [96]
    const unsigned long long lmlt = (1ull << lane) - 1ull;

    // pass 1: definitely-kept (key > thr+W)
    int base = 0;
    float psum = 0.f;
    #pragma unroll
    for (int e = 0; e < 32; e++) {
      bool def = key[e] > hik;
      float pv = def ? __expf(k2f(key[e]) - Mrow) : 0.f;
      psum += pv;
      unsigned long long mk = __ballot(def);
      if (def) {
        int pos = base + __popcll(mk & lmlt);
        Pl[pos] = pv; Jl[pos] = lane + 64 * e;
      }
      base += __popcll(mk);
    }
    // pass 2: boundary candidates
    int mcand = 0;
    #pragma unroll
    for (int e = 0; e < 32; e++) {
      bool cand = (key[e] >= lok) && (key[e] <= hik);
      unsigned long long mk = __ballot(cand);
      if (cand) {
        int pos = mcand + __popcll(mk & lmlt);
        if (pos < 32) Jc[pos] = lane + 64 * e;
      }
      mcand += __popcll(mk);
    }
    if (mcand > 32) mcand = 32;

    // exact f32 recompute of candidate scores: s = q_s . (k_j + rel[ridx])
    const float qv = q32[((size_t)bh * Nn + i) * 64 + lane];
    for (int c = 0; c < mcand; c++) {
      int j = Jc[c];
      int ridx = i - j + 256;
      ridx = ridx < 0 ? 0 : (ridx > 255 ? 255 : ridx);
      float kv = k32[((size_t)bh * Nn + j) * 64 + lane];
      float rv = rel32[ridx * 64 + lane];
      float t = qv * (kv + rv);
      #pragma unroll
      for (int d = 1; d < 64; d <<= 1) t += __shfl_xor(t, d);
      if (lane == 0) Sx[c] = t;
    }
    const int need = topk - base;
    float myx = -3.4e38f;
    if (lane < mcand) myx = Sx[lane];
    int rank = 0;
    for (int c = 0; c < mcand; c++) rank += (Sx[c] > myx) ? 1 : 0;
    bool ck = (lane < mcand) && (rank < need);   // ties at boundary kept
    float pc = ck ? __expf(myx - Mrow) : 0.f;
    unsigned long long mk2 = __ballot(ck);
    if (ck) {
      int pos = base + __popcll(mk2 & lmlt);
      Pl[pos] = pc; Jl[pos] = Jc[lane];
    }
    base += __popcll(mk2);
    float csum = pc;
    #pragma unroll
    for (int d = 1; d < 64; d <<= 1) csum += __shfl_xor(csum, d);
    #pragma unroll
    for (int d = 1; d < 64; d <<= 1) psum += __shfl_xor(psum, d);
    const float denom = psum + csum;
    const float coef = gating[(size_t)b * Nn + i] / denom;
    const int nk = base;

    // PV gather: out[d=lane] = coef * sum p_t * v[j_t][lane]
    float a0 = 0, a1 = 0, a2 = 0, a3 = 0;
    const size_t vb = (size_t)bh * Nn * 64;
    int t4 = nk & ~3;
    for (int t = 0; t < t4; t += 4) {
      float p0 = Pl[t], p1 = Pl[t + 1], p2 = Pl[t + 2], p3 = Pl[t + 3];
      int j0 = Jl[t], j1 = Jl[t + 1], j2 = Jl[t + 2], j3 = Jl[t + 3];
      a0 += p0 * bf2f(vbf[vb + (size_t)j0 * 64 + lane]);
      a1 += p1 * bf2f(vbf[vb + (size_t)j1 * 64 + lane]);
      a2 += p2 * bf2f(vbf[vb + (size_t)j2 * 64 + lane]);
      a3 += p3 * bf2f(vbf[vb + (size_t)j3 * 64 + lane]);
    }
    for (int t = t4; t < nk; t++)
      a0 += Pl[t] * bf2f(vbf[vb + (size_t)Jl[t] * 64 + lane]);
    float outv = (a0 + a1 + a2 + a3) * coef;
    inner[((size_t)b * Nn + i) * 1024 + h * 64 + lane] = f2bf(outv);
  }
}

extern "C" void kernel_launch(void* const* d_in, const int* in_sizes, int n_in,
                              void* d_out, int out_size, void* d_ws, size_t ws_size,
                              hipStream_t stream) {
  const float* x      = (const float*)d_in[0];
  const float* gating = (const float*)d_in[1];
  const float* Wq     = (const float*)d_in[2];
  const float* bq     = (const float*)d_in[3];
  const float* Wkv    = (const float*)d_in[4];
  const float* bkv    = (const float*)d_in[5];
  const float* Wo     = (const float*)d_in[6];
  const float* bo     = (const float*)d_in[7];
  const float* rel    = (const float*)d_in[8];
  const int*   topk   = (const int*)d_in[10];
  float* out = (float*)d_out;

  char* ws = (char*)d_ws;
  size_t off = 0;
  auto alloc = [&](size_t bytes) -> void* {
    void* p = ws + off; off += (bytes + 255) & ~(size_t)255; return p;
  };
  unsigned short* Wqt0 = (unsigned short*)alloc(1024ull * 1024 * 2);
  unsigned short* Wqt1 = (unsigned short*)alloc(1024ull * 1024 * 2);
  unsigned short* Wqt2 = (unsigned short*)alloc(1024ull * 1024 * 2);
  unsigned short* Wkt0 = (unsigned short*)alloc(2048ull * 1024 * 2);
  unsigned short* Wkt1 = (unsigned short*)alloc(2048ull * 1024 * 2);
  unsigned short* Wkt2 = (unsigned short*)alloc(2048ull * 1024 * 2);
  unsigned short* Wot0 = (unsigned short*)alloc(1024ull * 1024 * 2);
  unsigned short* relbf = (unsigned short*)alloc(256ull * 64 * 2);
  float* q32 = (float*)alloc((size_t)BHn * Nn * 64 * 4);
  float* k32 = (float*)alloc((size_t)BHn * Nn * 64 * 4);
  unsigned short* qbf = (unsigned short*)alloc((size_t)BHn * Nn * 64 * 2);
  unsigned short* kbf = (unsigned short*)alloc((size_t)BHn * Nn * 64 * 2);
  unsigned short* vbf = (unsigned short*)alloc((size_t)BHn * Nn * 64 * 2);
  unsigned short* innerbf = (unsigned short*)alloc((size_t)Bn * Nn * 1024 * 2);
  if (off > ws_size) return;  // workspace too small -> loud validation fail

  size_t shmem = 16 * 2052 * 4 + 128 * 72 * 2 + 16 * 264 * 2;  // 158208 B
  (void)hipFuncSetAttribute((const void*)attn_k,
                            hipFuncAttributeMaxDynamicSharedMemorySize, (int)shmem);

  transpose_split<<<dim3(32, 32), 256, 0, stream>>>(Wq, Wqt0, Wqt1, Wqt2, 1024, 1024);
  transpose_split<<<dim3(64, 32), 256, 0, stream>>>(Wkv, Wkt0, Wkt1, Wkt2, 1024, 2048);
  transpose_split<<<dim3(32, 32), 256, 0, stream>>>(Wo, Wot0, nullptr, nullptr, 1024, 1024);
  convert_bf16<<<dim3(64), 256, 0, stream>>>(rel, relbf, 256 * 64);

  // q = (x@Wq + bq) * 1/8  (scale folded; exact pow2)
  gemm_k<3><<<dim3(8, 64), 256, 0, stream>>>(x, Wqt0, Wqt1, Wqt2, bq,
      q32, qbf, vbf, 8192, 1024, 1024, 0.125f, 0);
  // k | v = x@Wkv + bkv
  gemm_k<3><<<dim3(16, 64), 256, 0, stream>>>(x, Wkt0, Wkt1, Wkt2, bkv,
      k32, kbf, vbf, 8192, 2048, 1024, 1.0f, 0);

  attn_k<<<dim3(128, 64), 512, shmem, stream>>>(qbf, kbf, vbf, q32, k32,
      rel, relbf, gating, topk, innerbf);

  // out = inner@Wo + bo
  gemm_k<1><<<dim3(8, 64), 256, 0, stream>>>(innerbf, Wot0, Wot0, Wot0, bo,
      out, nullptr, nullptr, 8192, 1024, 1024, 1.0f, 1);
}

// Round 4
// 1293.849 us; speedup vs baseline: 2.1060x; 2.1060x over previous
//
#include <hip/hip_runtime.h>
#include <stdint.h>

// Sparse top-k attention (B=4,N=2048,H=16,DH=64, topk=64).
// Selection must match numpy f32 selection: q32/k32 are ~f32-exact (6-term
// 3-word-split MFMA GEMM); bulk scores are 3-term 2-word MFMA stored f16
// (provable |err| <= DELTA=1.25e-3); rank-64 threshold by 10-step value-space
// bisection; boundary candidates recomputed from q32/k32 with f64
// accumulation and ranked exactly. Weight noise floors all << 1e-3.

typedef __attribute__((ext_vector_type(8))) short short8;
typedef __attribute__((ext_vector_type(4))) float floatx4;

#define Bn   4
#define Nn   2048
#define Hn   16
#define BHn  (Bn*Hn)
#define DELTA 0.00125f

__device__ __forceinline__ float bf2f(unsigned short u) {
  union { unsigned int i; float f; } v; v.i = ((unsigned int)u) << 16; return v.f;
}
__device__ __forceinline__ unsigned short f2bf(float f) {
  union { float f; unsigned int i; } v; v.f = f;
  unsigned int r = v.i + 0x7fffu + ((v.i >> 16) & 1u);
  return (unsigned short)(r >> 16);
}
__device__ __forceinline__ floatx4 mfma16(short8 a, short8 b, floatx4 c) {
  return __builtin_amdgcn_mfma_f32_16x16x32_bf16(a, b, c, 0, 0, 0);
}
// 2-word bf16 split: x ~= h + m (16 mantissa bits)
__device__ __forceinline__ void split2(float x, unsigned short& h, unsigned short& m) {
  h = f2bf(x);
  m = f2bf(x - bf2f(h));
}
// 3-word bf16 split: x == h + m + l to ~24 mantissa bits
__device__ __forceinline__ void split3(float x, unsigned short& h, unsigned short& m, unsigned short& l) {
  h = f2bf(x);
  float r = x - bf2f(h);
  m = f2bf(r);
  l = f2bf(r - bf2f(m));
}

// ---- W[K][N] f32 -> T0/T1/T2[N][K] bf16 3-word split
__global__ __launch_bounds__(256)
void transpose_split3(const float* __restrict__ W,
                      unsigned short* __restrict__ T0,
                      unsigned short* __restrict__ T1,
                      unsigned short* __restrict__ T2,
                      int K, int Ncols)
{
  __shared__ float tile[32][33];
  int k0 = blockIdx.y * 32, n0 = blockIdx.x * 32;
  int tx = threadIdx.x & 31, ty = threadIdx.x >> 5;
  for (int s = 0; s < 32; s += 8)
    tile[ty + s][tx] = W[(size_t)(k0 + ty + s) * Ncols + n0 + tx];
  __syncthreads();
  for (int s = 0; s < 32; s += 8) {
    float x = tile[tx][ty + s];
    unsigned short h, m, l;
    split3(x, h, m, l);
    size_t o = (size_t)(n0 + ty + s) * K + k0 + tx;
    T0[o] = h; T1[o] = m; T2[o] = l;
  }
}

// ---- W[K][N] f32 -> T0/T1[N][K] bf16 2-word split (output GEMM weights)
__global__ __launch_bounds__(256)
void transpose_split2(const float* __restrict__ W,
                      unsigned short* __restrict__ T0,
                      unsigned short* __restrict__ T1,
                      int K, int Ncols)
{
  __shared__ float tile[32][33];
  int k0 = blockIdx.y * 32, n0 = blockIdx.x * 32;
  int tx = threadIdx.x & 31, ty = threadIdx.x >> 5;
  for (int s = 0; s < 32; s += 8)
    tile[ty + s][tx] = W[(size_t)(k0 + ty + s) * Ncols + n0 + tx];
  __syncthreads();
  for (int s = 0; s < 32; s += 8) {
    float x = tile[tx][ty + s];
    unsigned short h, m;
    split2(x, h, m);
    size_t o = (size_t)(n0 + ty + s) * K + k0 + tx;
    T0[o] = h; T1[o] = m;
  }
}

__global__ __launch_bounds__(256)
void convert_bf16(const float* __restrict__ in, unsigned short* __restrict__ outp, int n) {
  int i = blockIdx.x * 256 + threadIdx.x;
  if (i < n) outp[i] = f2bf(in[i]);
}

// ---- QKV GEMM: C = A(f32)*Bt^T + bias, A split3 on the fly, B 3-word,
// 6 MFMA terms (hh,hm,mh,mm,hl,lh) -> ~f32-exact. Head-split outputs:
// nl<1024: O32 f32 + 2-word bf16 (Oh,Om); nl>=1024: Vh bf16.
__global__ __launch_bounds__(256)
void gemm_qkv(const float* __restrict__ A,
              const unsigned short* __restrict__ B0,
              const unsigned short* __restrict__ B1,
              const unsigned short* __restrict__ B2,
              const float* __restrict__ bias,
              float* __restrict__ O32,
              unsigned short* __restrict__ Oh,
              unsigned short* __restrict__ Om,
              unsigned short* __restrict__ Vh,
              int K, float scale)
{
  __shared__ unsigned short lA[3][128 * 40];
  __shared__ unsigned short lB[3][128 * 40];
  const int tid = threadIdx.x;
  const int lane = tid & 63;
  const int m0 = blockIdx.y * 128, n0 = blockIdx.x * 128;
  const int wid = tid >> 6, wm = wid >> 1, wn = wid & 1;
  const int fr = lane & 15, fq = lane >> 4;
  floatx4 acc[4][4] = {};

  for (int k0 = 0; k0 < K; k0 += 32) {
    __syncthreads();
    #pragma unroll
    for (int p = 0; p < 2; p++) {
      int c = tid + p * 256;
      int row = c >> 2, kc = (c & 3) * 8;
      size_t go = (size_t)(m0 + row) * K + k0 + kc;
      float4 v0 = *(const float4*)&A[go];
      float4 v1 = *(const float4*)&A[go + 4];
      union { unsigned short u[8]; uint4 q; } hh, mm, ll;
      float xs[8] = {v0.x, v0.y, v0.z, v0.w, v1.x, v1.y, v1.z, v1.w};
      #pragma unroll
      for (int e = 0; e < 8; e++) split3(xs[e], hh.u[e], mm.u[e], ll.u[e]);
      *(uint4*)&lA[0][row * 40 + kc] = hh.q;
      *(uint4*)&lA[1][row * 40 + kc] = mm.q;
      *(uint4*)&lA[2][row * 40 + kc] = ll.q;
      size_t bo = (size_t)(n0 + row) * K + k0 + kc;
      *(uint4*)&lB[0][row * 40 + kc] = *(const uint4*)&B0[bo];
      *(uint4*)&lB[1][row * 40 + kc] = *(const uint4*)&B1[bo];
      *(uint4*)&lB[2][row * 40 + kc] = *(const uint4*)&B2[bo];
    }
    __syncthreads();
    short8 af[3][4], bfr[3][4];
    #pragma unroll
    for (int s = 0; s < 3; s++)
      #pragma unroll
      for (int t = 0; t < 4; t++) {
        af[s][t]  = *(const short8*)&lA[s][(wm * 64 + t * 16 + fr) * 40 + 8 * fq];
        bfr[s][t] = *(const short8*)&lB[s][(wn * 64 + t * 16 + fr) * 40 + 8 * fq];
      }
    #pragma unroll
    for (int mi = 0; mi < 4; mi++)
      #pragma unroll
      for (int ni = 0; ni < 4; ni++) {
        acc[mi][ni] = mfma16(af[0][mi], bfr[0][ni], acc[mi][ni]);
        acc[mi][ni] = mfma16(af[0][mi], bfr[1][ni], acc[mi][ni]);
        acc[mi][ni] = mfma16(af[1][mi], bfr[0][ni], acc[mi][ni]);
        acc[mi][ni] = mfma16(af[1][mi], bfr[1][ni], acc[mi][ni]);
        acc[mi][ni] = mfma16(af[0][mi], bfr[2][ni], acc[mi][ni]);
        acc[mi][ni] = mfma16(af[2][mi], bfr[0][ni], acc[mi][ni]);
      }
  }
  // C/D frag: row=(lane>>4)*4+rg, col=lane&15
  #pragma unroll
  for (int mi = 0; mi < 4; mi++)
    #pragma unroll
    for (int ni = 0; ni < 4; ni++) {
      int nl = n0 + wn * 64 + ni * 16 + fr;
      float bv = bias[nl];
      #pragma unroll
      for (int rg = 0; rg < 4; rg++) {
        int ml = m0 + wm * 64 + mi * 16 + fq * 4 + rg;
        float val = (acc[mi][ni][rg] + bv) * scale;
        int bb = ml >> 11, ii = ml & 2047;
        int hh2 = (nl & 1023) >> 6, dd = nl & 63;
        size_t idx = (((size_t)bb * Hn + hh2) * Nn + ii) * 64 + dd;
        if (nl < 1024) {
          O32[idx] = val;
          unsigned short h, m;
          split2(val, h, m);
          Oh[idx] = h; Om[idx] = m;
        } else {
          Vh[idx] = f2bf(val);
        }
      }
    }
}

// ---- output GEMM: C = A(f32)*Bt^T + bias, A split2 on the fly, B 2-word,
// 3 MFMA terms, f32 out.
__global__ __launch_bounds__(256)
void gemm_out(const float* __restrict__ A,
              const unsigned short* __restrict__ B0,
              const unsigned short* __restrict__ B1,
              const float* __restrict__ bias,
              float* __restrict__ O32,
              int Ncols, int K)
{
  __shared__ unsigned short lA[2][128 * 40];
  __shared__ unsigned short lB[2][128 * 40];
  const int tid = threadIdx.x;
  const int lane = tid & 63;
  const int m0 = blockIdx.y * 128, n0 = blockIdx.x * 128;
  const int wid = tid >> 6, wm = wid >> 1, wn = wid & 1;
  const int fr = lane & 15, fq = lane >> 4;
  floatx4 acc[4][4] = {};

  for (int k0 = 0; k0 < K; k0 += 32) {
    __syncthreads();
    #pragma unroll
    for (int p = 0; p < 2; p++) {
      int c = tid + p * 256;
      int row = c >> 2, kc = (c & 3) * 8;
      size_t go = (size_t)(m0 + row) * K + k0 + kc;
      float4 v0 = *(const float4*)&A[go];
      float4 v1 = *(const float4*)&A[go + 4];
      union { unsigned short u[8]; uint4 q; } hh, mm;
      float xs[8] = {v0.x, v0.y, v0.z, v0.w, v1.x, v1.y, v1.z, v1.w};
      #pragma unroll
      for (int e = 0; e < 8; e++) split2(xs[e], hh.u[e], mm.u[e]);
      *(uint4*)&lA[0][row * 40 + kc] = hh.q;
      *(uint4*)&lA[1][row * 40 + kc] = mm.q;
      size_t bo = (size_t)(n0 + row) * K + k0 + kc;
      *(uint4*)&lB[0][row * 40 + kc] = *(const uint4*)&B0[bo];
      *(uint4*)&lB[1][row * 40 + kc] = *(const uint4*)&B1[bo];
    }
    __syncthreads();
    short8 af[2][4], bfr[2][4];
    #pragma unroll
    for (int s = 0; s < 2; s++)
      #pragma unroll
      for (int t = 0; t < 4; t++) {
        af[s][t]  = *(const short8*)&lA[s][(wm * 64 + t * 16 + fr) * 40 + 8 * fq];
        bfr[s][t] = *(const short8*)&lB[s][(wn * 64 + t * 16 + fr) * 40 + 8 * fq];
      }
    #pragma unroll
    for (int mi = 0; mi < 4; mi++)
      #pragma unroll
      for (int ni = 0; ni < 4; ni++) {
        acc[mi][ni] = mfma16(af[0][mi], bfr[0][ni], acc[mi][ni]);
        acc[mi][ni] = mfma16(af[0][mi], bfr[1][ni], acc[mi][ni]);
        acc[mi][ni] = mfma16(af[1][mi], bfr[0][ni], acc[mi][ni]);
      }
  }
  #pragma unroll
  for (int mi = 0; mi < 4; mi++)
    #pragma unroll
    for (int ni = 0; ni < 4; ni++) {
      int nl = n0 + wn * 64 + ni * 16 + fr;
      float bv = bias[nl];
      #pragma unroll
      for (int rg = 0; rg < 4; rg++) {
        int ml = m0 + wm * 64 + mi * 16 + fq * 4 + rg;
        O32[(size_t)ml * Ncols + nl] = acc[mi][ni][rg] + bv;
      }
    }
}

// ---- attention: one WG (8 waves / 512 thr) = 16 query rows of one (b,h)
__global__ __launch_bounds__(512, 4)
void attn_k(const unsigned short* __restrict__ qh,
            const unsigned short* __restrict__ qm,
            const unsigned short* __restrict__ kh,
            const unsigned short* __restrict__ km,
            const unsigned short* __restrict__ vh,
            const float* __restrict__ q32,
            const float* __restrict__ k32,
            const unsigned short* __restrict__ relbf,
            const float* __restrict__ rel32,
            const float* __restrict__ gating,
            const int* __restrict__ topkp,
            float* __restrict__ inner)
{
  extern __shared__ char smem[];
  _Float16* S = (_Float16*)smem;                     // [16][2048] 65536B
  unsigned short* KtH = (unsigned short*)(smem + 65536);  // [64][64] 8192B
  unsigned short* KtM = KtH + 4096;                       // [64][64] 8192B
  _Float16* qE = (_Float16*)KtH;                     // [16][256] after QK^T

  const int ib = blockIdx.x, bh = blockIdx.y;
  const int i0 = ib * 16;
  const int b = bh >> 4, h = bh & 15;
  const int tid = threadIdx.x;
  const int lane = tid & 63, w = tid >> 6;
  const int fr = lane & 15, fq = lane >> 4;
  const int topk = topkp[0];

  // q A-fragments, 2-word (A row = lane&15, k = 8*(lane>>4)+e)
  const size_t qoff = ((size_t)bh * Nn + i0) * 64;
  const size_t qf = qoff + (size_t)fr * 64 + 8 * fq;
  const short8 aqh0 = *(const short8*)&qh[qf];
  const short8 aqh1 = *(const short8*)&qh[qf + 32];
  const short8 aqm0 = *(const short8*)&qm[qf];
  const short8 aqm1 = *(const short8*)&qm[qf + 32];

  // QK^T: 32 tiles of 64 cols; waves 0-3 do even tiles, 4-7 odd
  for (int jt = 0; jt < 32; jt++) {
    __syncthreads();
    {
      int row = tid >> 3, dc = (tid & 7) * 8;
      size_t g = ((size_t)bh * Nn + jt * 64 + row) * 64 + dc;
      *(uint4*)&KtH[row * 64 + dc] = *(const uint4*)&kh[g];
      *(uint4*)&KtM[row * 64 + dc] = *(const uint4*)&km[g];
    }
    __syncthreads();
    if ((jt & 1) == (w >> 2)) {
      int wc = w & 3;
      int kb = (wc * 16 + fr) * 64 + 8 * fq;
      short8 kh0 = *(const short8*)&KtH[kb];
      short8 kh1 = *(const short8*)&KtH[kb + 32];
      short8 km0 = *(const short8*)&KtM[kb];
      short8 km1 = *(const short8*)&KtM[kb + 32];
      floatx4 c = {};
      c = mfma16(aqh0, kh0, c); c = mfma16(aqh1, kh1, c);
      c = mfma16(aqh0, km0, c); c = mfma16(aqh1, km1, c);
      c = mfma16(aqm0, kh0, c); c = mfma16(aqm1, kh1, c);
      #pragma unroll
      for (int rg = 0; rg < 4; rg++)
        S[(fq * 4 + rg) * 2048 + jt * 64 + wc * 16 + fr] = (_Float16)c[rg];
    }
  }
  __syncthreads();

  // qE[i_local][r] = q_i . rel_r  (KtH region now free)
  #pragma unroll
  for (int rs = 0; rs < 2; rs++) {
    int r0 = (w * 2 + rs) * 16;
    size_t rf = (size_t)(r0 + fr) * 64 + 8 * fq;
    short8 rb0 = *(const short8*)&relbf[rf];
    short8 rb1 = *(const short8*)&relbf[rf + 32];
    floatx4 c = {};
    c = mfma16(aqh0, rb0, c); c = mfma16(aqh1, rb1, c);
    c = mfma16(aqm0, rb0, c); c = mfma16(aqm1, rb1, c);
    #pragma unroll
    for (int rg = 0; rg < 4; rg++)
      qE[(fq * 4 + rg) * 256 + r0 + fr] = (_Float16)c[rg];
  }
  __syncthreads();

  // per-row selection + softmax + PV (wave w owns rows 2w, 2w+1)
  #pragma unroll 1
  for (int rr = 0; rr < 2; rr++) {
    const int r = w * 2 + rr;
    const int i = i0 + r;
    const _Float16* Srow = S + r * 2048;
    const _Float16* qErow = qE + r * 256;

    float key[32];
    float mx = -3.0e38f, sum = 0.f, ssq = 0.f;
    #pragma unroll
    for (int e = 0; e < 16; e++) {
      int j0 = 2 * lane + 128 * e;
      union { unsigned int u; _Float16 hx[2]; } sv;
      sv.u = *(const unsigned int*)&Srow[j0];
      int r0i = i - j0 + 256;
      int c0 = r0i < 0 ? 0 : (r0i > 255 ? 255 : r0i);
      int r1i = r0i - 1;
      int c1 = r1i < 0 ? 0 : (r1i > 255 ? 255 : r1i);
      float s0 = (float)sv.hx[0] + (float)qErow[c0];
      float s1 = (float)sv.hx[1] + (float)qErow[c1];
      key[2 * e] = s0; key[2 * e + 1] = s1;
      mx = fmaxf(mx, fmaxf(s0, s1));
      sum += s0 + s1;
      ssq += s0 * s0 + s1 * s1;
    }
    #pragma unroll
    for (int d = 1; d < 64; d <<= 1) {
      mx = fmaxf(mx, __shfl_xor(mx, d));
      sum += __shfl_xor(sum, d);
      ssq += __shfl_xor(ssq, d);
    }
    const float mu = sum * (1.f / 2048.f);
    const float sg = sqrtf(fmaxf(ssq * (1.f / 2048.f) - mu * mu, 0.f)) + 1e-9f;

    auto cntGE = [&](float u) -> int {
      int c = 0;
      #pragma unroll
      for (int e = 0; e < 32; e++) c += (key[e] >= u) ? 1 : 0;
      #pragma unroll
      for (int d = 1; d < 64; d <<= 1) c += __shfl_xor(c, d);
      return c;
    };

    float lo = mu + 1.6f * sg;
    float hi = mx + fabsf(mx) * 1e-6f + 1e-20f;
    int cl = cntGE(lo);
    #pragma unroll 1
    for (int t = 0; t < 6 && cl < topk; t++) {
      hi = lo; lo -= (0.8f + 0.4f * t) * sg; cl = cntGE(lo);
    }
    if (cl < topk) lo = -3.0e38f;
    #pragma unroll 1
    for (int it = 0; it < 10; it++) {
      float mid = 0.5f * (lo + hi);
      if (cntGE(mid) >= topk) lo = mid; else hi = mid;
    }
    // provably-safe cuts: |stored - true| <= DELTA
    const float C = hi + 2.0f * DELTA;   // a>=C  =>  true > vk_true
    const float L = lo - 2.0f * DELTA;   // true top-64  =>  a >= L

    // scratch aliased into this row's S span (keys fully in regs)
    char* sb = (char*)Srow;
    float* Pl = (float*)(sb);           // [128] score -> p
    int*   Jl = (int*)(sb + 512);       // [128]
    float* Sx = (float*)(sb + 1024);    // [64] cand exact score
    int*   Jc = (int*)(sb + 1280);      // [64]
    asm volatile("" ::: "memory");
    const unsigned long long lmlt = (1ull << lane) - 1ull;

    // pass 1: definitely-kept (a >= C; base < topk by construction)
    int base = 0;
    #pragma unroll
    for (int e2 = 0; e2 < 32; e2++) {
      bool dk = key[e2] >= C;
      unsigned long long mk = __ballot(dk);
      if (dk) {
        int pos = base + __popcll(mk & lmlt);
        Pl[pos] = key[e2]; Jl[pos] = 2 * lane + 128 * (e2 >> 1) + (e2 & 1);
      }
      base += __popcll(mk);
    }
    // pass 2: boundary candidates in [L, C)
    int mcand = 0;
    #pragma unroll
    for (int e2 = 0; e2 < 32; e2++) {
      bool cd = (key[e2] >= L) && (key[e2] < C);
      unsigned long long mk = __ballot(cd);
      if (cd) {
        int pos = mcand + __popcll(mk & lmlt);
        if (pos < 64) Jc[pos] = 2 * lane + 128 * (e2 >> 1) + (e2 & 1);
      }
      mcand += __popcll(mk);
    }
    if (mcand > 64) mcand = 64;
    asm volatile("" ::: "memory");

    // exact recompute of candidates from f32 q32/k32, f64 accumulation:
    // s = q32 . (k32 + rel)   [q32/k32 are ~f32-exact vs reference]
    const size_t qrow = ((size_t)bh * Nn + i) * 64 + lane;
    const double qv = (double)q32[qrow];
    #pragma unroll 1
    for (int c2 = 0; c2 < mcand; c2++) {
      int j = Jc[c2];
      int ridx = i - j + 256;
      ridx = ridx < 0 ? 0 : (ridx > 255 ? 255 : ridx);
      size_t krow = ((size_t)bh * Nn + j) * 64 + lane;
      double t = qv * ((double)k32[krow] + (double)rel32[ridx * 64 + lane]);
      #pragma unroll
      for (int d = 1; d < 64; d <<= 1) t += __shfl_xor(t, d);
      if (lane == 0) Sx[c2] = (float)t;
    }
    asm volatile("" ::: "memory");

    // rank candidates by EXACT score, deterministic tie-break by slot
    const int need = topk - base;
    float myx = (lane < mcand) ? Sx[lane] : -3.0e38f;
    int rank = 0;
    #pragma unroll 1
    for (int c2 = 0; c2 < mcand; c2++) {
      float o = Sx[c2];
      rank += (o > myx || (o == myx && c2 < lane)) ? 1 : 0;
    }
    bool ck = (lane < mcand) && (rank < need);
    unsigned long long mk2 = __ballot(ck);
    if (ck) {
      int pos = base + __popcll(mk2 & lmlt);
      Pl[pos] = myx; Jl[pos] = Jc[lane];
    }
    base += __popcll(mk2);
    const int nk = base;
    asm volatile("" ::: "memory");

    // exp + denom (lane-parallel over kept list)
    float p = 0.f;
    if (lane < nk) { p = __expf(Pl[lane] - mx); Pl[lane] = p; }
    float psum = p;
    #pragma unroll
    for (int d = 1; d < 64; d <<= 1) psum += __shfl_xor(psum, d);
    const float coef = gating[(size_t)b * Nn + i] / psum;
    asm volatile("" ::: "memory");

    // PV gather: out[d=lane] = coef * sum p_t * v[j_t][lane]
    float a0 = 0, a1 = 0, a2 = 0, a3 = 0;
    const size_t vb = (size_t)bh * Nn * 64;
    int t4 = nk & ~3;
    #pragma unroll 1
    for (int t = 0; t < t4; t += 4) {
      float p0 = Pl[t], p1 = Pl[t + 1], p2 = Pl[t + 2], p3 = Pl[t + 3];
      int j0 = Jl[t], j1 = Jl[t + 1], j2 = Jl[t + 2], j3 = Jl[t + 3];
      a0 += p0 * bf2f(vh[vb + (size_t)j0 * 64 + lane]);
      a1 += p1 * bf2f(vh[vb + (size_t)j1 * 64 + lane]);
      a2 += p2 * bf2f(vh[vb + (size_t)j2 * 64 + lane]);
      a3 += p3 * bf2f(vh[vb + (size_t)j3 * 64 + lane]);
    }
    for (int t = t4; t < nk; t++)
      a0 += Pl[t] * bf2f(vh[vb + (size_t)Jl[t] * 64 + lane]);
    float outv = (a0 + a1 + a2 + a3) * coef;
    inner[((size_t)b * Nn + i) * 1024 + h * 64 + lane] = outv;
  }
}

extern "C" void kernel_launch(void* const* d_in, const int* in_sizes, int n_in,
                              void* d_out, int out_size, void* d_ws, size_t ws_size,
                              hipStream_t stream) {
  const float* x      = (const float*)d_in[0];
  const float* gating = (const float*)d_in[1];
  const float* Wq     = (const float*)d_in[2];
  const float* bq     = (const float*)d_in[3];
  const float* Wkv    = (const float*)d_in[4];
  const float* bkv    = (const float*)d_in[5];
  const float* Wo     = (const float*)d_in[6];
  const float* bo     = (const float*)d_in[7];
  const float* rel    = (const float*)d_in[8];
  const int*   topk   = (const int*)d_in[10];
  float* out = (float*)d_out;

  char* ws = (char*)d_ws;
  size_t off = 0;
  auto alloc = [&](size_t bytes) -> void* {
    void* p = ws + off; off += (bytes + 255) & ~(size_t)255; return p;
  };
  unsigned short* Wqt0 = (unsigned short*)alloc(1024ull * 1024 * 2);
  unsigned short* Wqt1 = (unsigned short*)alloc(1024ull * 1024 * 2);
  unsigned short* Wqt2 = (unsigned short*)alloc(1024ull * 1024 * 2);
  unsigned short* Wkt0 = (unsigned short*)alloc(2048ull * 1024 * 2);
  unsigned short* Wkt1 = (unsigned short*)alloc(2048ull * 1024 * 2);
  unsigned short* Wkt2 = (unsigned short*)alloc(2048ull * 1024 * 2);
  unsigned short* Wot0 = (unsigned short*)alloc(1024ull * 1024 * 2);
  unsigned short* Wot1 = (unsigned short*)alloc(1024ull * 1024 * 2);
  unsigned short* relbf = (unsigned short*)alloc(256ull * 64 * 2);
  float* q32 = (float*)alloc((size_t)BHn * Nn * 64 * 4);
  float* k32 = (float*)alloc((size_t)BHn * Nn * 64 * 4);
  unsigned short* qhb = (unsigned short*)alloc((size_t)BHn * Nn * 64 * 2);
  unsigned short* qmb = (unsigned short*)alloc((size_t)BHn * Nn * 64 * 2);
  unsigned short* khb = (unsigned short*)alloc((size_t)BHn * Nn * 64 * 2);
  unsigned short* kmb = (unsigned short*)alloc((size_t)BHn * Nn * 64 * 2);
  unsigned short* vhb = (unsigned short*)alloc((size_t)BHn * Nn * 64 * 2);
  float* inner = (float*)alloc((size_t)Bn * Nn * 1024 * 4);
  if (off > ws_size) return;  // workspace too small -> loud validation fail

  size_t shmem = 65536 + 16384;  // 81920 B -> 2 WG/CU
  (void)hipFuncSetAttribute((const void*)attn_k,
                            hipFuncAttributeMaxDynamicSharedMemorySize, (int)shmem);

  transpose_split3<<<dim3(32, 32), 256, 0, stream>>>(Wq, Wqt0, Wqt1, Wqt2, 1024, 1024);
  transpose_split3<<<dim3(64, 32), 256, 0, stream>>>(Wkv, Wkt0, Wkt1, Wkt2, 1024, 2048);
  transpose_split2<<<dim3(32, 32), 256, 0, stream>>>(Wo, Wot0, Wot1, 1024, 1024);
  convert_bf16<<<dim3(64), 256, 0, stream>>>(rel, relbf, 256 * 64);

  // q = (x@Wq + bq) * 1/8  (scale folded; exact pow2)
  gemm_qkv<<<dim3(8, 64), 256, 0, stream>>>(x, Wqt0, Wqt1, Wqt2, bq,
      q32, qhb, qmb, qhb, 1024, 0.125f);
  // k | v = x@Wkv + bkv
  gemm_qkv<<<dim3(16, 64), 256, 0, stream>>>(x, Wkt0, Wkt1, Wkt2, bkv,
      k32, khb, kmb, vhb, 1024, 1.0f);

  attn_k<<<dim3(128, 64), 512, shmem, stream>>>(qhb, qmb, khb, kmb, vhb,
      q32, k32, relbf, rel, gating, topk, inner);

  // out = inner@Wo + bo
  gemm_out<<<dim3(8, 64), 256, 0, stream>>>(inner, Wot0, Wot1, bo,
      out, 1024, 1024);
}